// Round 5
// baseline (1019.413 us; speedup 1.0000x reference)
//
#include <hip/hip_runtime.h>
#include <hip/hip_fp16.h>

// RandDCGRUCell on MI355X.
// B=64, N=2000, IN_DIM=2, U=64, D=66, NSUP=2, K=2, M=5.
// Pipeline: build ELL sparse supports -> per gconv: build x0 (fp16), 4 SpMMs
// (Chebyshev, fp16 storage / fp32 accum), fp32 projection with fused
// sigmoid / tanh+GRU epilogue.
// R4 post-mortem: fp32 I/O confirmed (finite 0.322 error vs 0.108 threshold).
// Error source: log_sig=0 -> weights ~N(0,1); bf16 X rounding (2^-8) gives
// ~0.3 tail error. R5: X/VAL storage bf16 -> fp16 (2^-11 mantissa, 8x finer,
// same bytes). Predicted absmax ~0.04.

#define N_NODES 2000
#define BATCH   64
#define DFEAT   66
#define DPAD    72           // rows 144 B: 8B-aligned h4 loads, WROW/2 = 9*256
#define WROW    (BATCH*DPAD) // 4608
#define MMATS   5
#define KTOT    330          // DFEAT*MMATS
#define ELLW    128

typedef __half h16;

__device__ __forceinline__ __half2 f2h2(float a, float b) {
  __half2 r; r.x = __float2half_rn(a); r.y = __float2half_rn(b); return r;
}

struct h4 { __half2 a, b; };   // 8 B

// ---------------- weights: w = mu + exp(log_sig)*eps (fp32 out) -----
__global__ __launch_bounds__(256) void k_weights(
    const float* __restrict__ mu_w_ru, const float* __restrict__ ls_w_ru, const float* __restrict__ eps_w_ru,
    const float* __restrict__ mu_b_ru, const float* __restrict__ ls_b_ru, const float* __restrict__ eps_b_ru,
    const float* __restrict__ mu_w_c,  const float* __restrict__ ls_w_c,  const float* __restrict__ eps_w_c,
    const float* __restrict__ mu_b_c,  const float* __restrict__ ls_b_c,  const float* __restrict__ eps_b_c,
    float* __restrict__ Wru, float* __restrict__ bru,
    float* __restrict__ Wc,  float* __restrict__ bc)
{
  int idx = blockIdx.x*256 + threadIdx.x;
  const int n_wru = KTOT*128, n_wc = KTOT*64;
  if (idx < n_wru) {
    Wru[idx] = mu_w_ru[idx] + expf(ls_w_ru[idx]) * eps_w_ru[idx];
  } else if (idx < n_wru + n_wc) {
    int i = idx - n_wru;
    Wc[i] = mu_w_c[i] + expf(ls_w_c[i]) * eps_w_c[i];
  } else if (idx < n_wru + n_wc + 128) {
    int i = idx - n_wru - n_wc;
    bru[i] = mu_b_ru[i] + expf(ls_b_ru[i]) * eps_b_ru[i];
  } else if (idx < n_wru + n_wc + 128 + 64) {
    int i = idx - n_wru - n_wc - 128;
    bc[i] = mu_b_c[i] + expf(ls_b_c[i]) * eps_b_c[i];
  }
}

// ---------------- ELL build (order within row irrelevant for a sum) --
__global__ __launch_bounds__(256) void k_ell(
    const float* __restrict__ supp, unsigned short* __restrict__ cols,
    float* __restrict__ vals, int* __restrict__ cnt)
{
  int j = blockIdx.x*256 + threadIdx.x;
  if (j >= N_NODES) return;
  int n = blockIdx.y, s = blockIdx.z;
  int r = s*N_NODES + n;
  float v = supp[(size_t)r*N_NODES + j];
  if (v != 0.f) {
    int p = atomicAdd(cnt + r, 1);
    if (p < ELLW) {
      cols[(size_t)r*ELLW + p] = (unsigned short)j;
      vals[(size_t)r*ELLW + p] = v;
    }
  }
}

// ---------------- build x0 [n][b][DPAD] fp16 ------------------------
__global__ __launch_bounds__(256) void k_build0(
    const float* __restrict__ inp, const float* __restrict__ hx,
    const h16* __restrict__ VALr, h16* __restrict__ xb, int mode)
{
  int n = blockIdx.x;
  for (int idx = threadIdx.x; idx < WROW; idx += 256) {
    int b = idx / DPAD, d = idx % DPAD;
    float v = 0.f;
    if (d < 2) {
      v = inp[(size_t)b*(N_NODES*2) + n*2 + d];
    } else if (d < DFEAT) {
      float hv = hx[(size_t)b*(N_NODES*64) + n*64 + (d-2)];
      if (mode == 1) hv *= __half2float(VALr[((size_t)b*N_NODES + n)*128 + (d-2)]); // r gate
      v = hv;
    }
    xb[(size_t)n*WROW + idx] = __float2half_rn(v);
  }
}

// ---------------- SpMM: x1 = S @ x0 (both supports, fp16) ------------
__global__ __launch_bounds__(256) void k_spmm(
    h16* __restrict__ dst0, h16* __restrict__ dst1,
    const h16* __restrict__ src, const unsigned short* __restrict__ cols,
    const float* __restrict__ vals, const int* __restrict__ cnt)
{
  const int n = blockIdx.x, s = blockIdx.y, t = threadIdx.x;
  const int r = s*N_NODES + n;
  int c = cnt[r]; if (c > ELLW) c = ELLW;
  const unsigned short* cp = cols + (size_t)r*ELLW;
  const float*          vp = vals + (size_t)r*ELLW;
  float2 acc[9];
  #pragma unroll
  for (int i = 0; i < 9; ++i) acc[i] = make_float2(0.f, 0.f);
  const __half2* sb = (const __half2*)src;
  for (int k = 0; k < c; ++k) {
    int j = cp[k]; float v = vp[k];
    const __half2* s0 = sb + (size_t)j*(WROW/2) + t;
    #pragma unroll
    for (int i = 0; i < 9; ++i) {
      float2 f = __half22float2(s0[i*256]);
      acc[i].x = fmaf(v, f.x, acc[i].x);
      acc[i].y = fmaf(v, f.y, acc[i].y);
    }
  }
  __half2* dp = (__half2*)(s ? dst1 : dst0) + (size_t)n*(WROW/2) + t;
  #pragma unroll
  for (int i = 0; i < 9; ++i) dp[i*256] = f2h2(acc[i].x, acc[i].y);
}

// ---------------- Chebyshev: x2 = 2*(S @ x1) - x0 (both supports) ----
__global__ __launch_bounds__(256) void k_cheb(
    h16* __restrict__ dst0, h16* __restrict__ dst1,
    const h16* __restrict__ src0, const h16* __restrict__ src1,
    const h16* __restrict__ x0, const unsigned short* __restrict__ cols,
    const float* __restrict__ vals, const int* __restrict__ cnt)
{
  const int n = blockIdx.x, s = blockIdx.y, t = threadIdx.x;
  const int r = s*N_NODES + n;
  int c = cnt[r]; if (c > ELLW) c = ELLW;
  const unsigned short* cp = cols + (size_t)r*ELLW;
  const float*          vp = vals + (size_t)r*ELLW;
  float2 acc[9];
  #pragma unroll
  for (int i = 0; i < 9; ++i) acc[i] = make_float2(0.f, 0.f);
  const __half2* sb = (const __half2*)(s ? src1 : src0);
  for (int k = 0; k < c; ++k) {
    int j = cp[k]; float v = vp[k];
    const __half2* s0 = sb + (size_t)j*(WROW/2) + t;
    #pragma unroll
    for (int i = 0; i < 9; ++i) {
      float2 f = __half22float2(s0[i*256]);
      acc[i].x = fmaf(v, f.x, acc[i].x);
      acc[i].y = fmaf(v, f.y, acc[i].y);
    }
  }
  const __half2* xp = (const __half2*)x0 + (size_t)n*(WROW/2) + t;
  __half2* dp = (__half2*)(s ? dst1 : dst0) + (size_t)n*(WROW/2) + t;
  #pragma unroll
  for (int i = 0; i < 9; ++i) {
    float2 f = __half22float2(xp[i*256]);
    dp[i*256] = f2h2(2.f*acc[i].x - f.x, 2.f*acc[i].y - f.y);
  }
}

// ---------------- projection: [64b x 330k] @ [330k x 64o] per (n,half)
// W staged in LDS in two m-chunks: m={0,1,2} (50,688B), m={3,4} (33,792B).
// mode 0: VAL[b][n][o0..] = sigmoid(acc+bias) fp16   (outw=128, hh=0,1)
// mode 1: out = u*hx + (1-u)*tanh(acc+bias)  fp32    (outw=64, hh=0)
__global__ __launch_bounds__(256) void k_proj(
    const h16* __restrict__ Xh, const float* __restrict__ W,
    const float* __restrict__ bias, h16* __restrict__ VAL,
    const float* __restrict__ hx, const h16* __restrict__ VALu,
    float* __restrict__ out, int outw, int mode)
{
  extern __shared__ float Wl[];          // max 66*3*64 fp32 = 50,688 B
  const int n = blockIdx.x, hh = blockIdx.y;
  const int t = threadIdx.x;
  const int og = t & 15, bg = t >> 4;    // 16 o-groups x 16 b-groups
  float acc[4][4];
  #pragma unroll
  for (int j = 0; j < 4; ++j)
    #pragma unroll
    for (int i = 0; i < 4; ++i) acc[j][i] = 0.f;

  const size_t NSF = (size_t)N_NODES * WROW;
  const h16* xn = Xh + (size_t)n*WROW;

  #pragma unroll
  for (int st = 0; st < 2; ++st) {
    const int m0 = st ? 3 : 0;
    const int nm = st ? 2 : 3;
    __syncthreads();                     // previous-stage readers done
    for (int i = t; i < DFEAT*64*nm; i += 256) {
      int o = i & 63, row = i >> 6;      // row = d*nm + mi
      int d = row / nm, mi = row - d*nm;
      Wl[i] = W[(d*MMATS + m0 + mi)*outw + hh*64 + o];
    }
    __syncthreads();

    for (int mi = 0; mi < nm; ++mi) {
      const h16* xm = xn + (size_t)(m0 + mi)*NSF;
      for (int d = 0; d < 64; d += 4) {
        float xv[4][4];
        #pragma unroll
        for (int j = 0; j < 4; ++j) {
          h4 u = *reinterpret_cast<const h4*>(xm + (bg*4 + j)*DPAD + d);
          float2 p = __half22float2(u.a), q = __half22float2(u.b);
          xv[j][0] = p.x; xv[j][1] = p.y;
          xv[j][2] = q.x; xv[j][3] = q.y;
        }
        #pragma unroll
        for (int kk = 0; kk < 4; ++kk) {
          float4 wv = *(const float4*)(&Wl[((d + kk)*nm + mi)*64 + og*4]);
          #pragma unroll
          for (int j = 0; j < 4; ++j) {
            float x = xv[j][kk];
            acc[j][0] = fmaf(x, wv.x, acc[j][0]);
            acc[j][1] = fmaf(x, wv.y, acc[j][1]);
            acc[j][2] = fmaf(x, wv.z, acc[j][2]);
            acc[j][3] = fmaf(x, wv.w, acc[j][3]);
          }
        }
      }
      #pragma unroll
      for (int dd = 64; dd < DFEAT; ++dd) {  // K tail (66 = 16*4 + 2)
        float4 wv = *(const float4*)(&Wl[(dd*nm + mi)*64 + og*4]);
        #pragma unroll
        for (int j = 0; j < 4; ++j) {
          float x = __half2float(xm[(bg*4 + j)*DPAD + dd]);
          acc[j][0] = fmaf(x, wv.x, acc[j][0]);
          acc[j][1] = fmaf(x, wv.y, acc[j][1]);
          acc[j][2] = fmaf(x, wv.z, acc[j][2]);
          acc[j][3] = fmaf(x, wv.w, acc[j][3]);
        }
      }
    }
  }

  const int o0 = hh*64 + og*4;
  if (mode == 0) {
    #pragma unroll
    for (int j = 0; j < 4; ++j) {
      int b = bg*4 + j;
      size_t base = ((size_t)b*N_NODES + n)*128 + o0;   // o0 % 4 == 0
      float s0 = 1.f/(1.f + expf(-(acc[j][0] + bias[o0+0])));
      float s1 = 1.f/(1.f + expf(-(acc[j][1] + bias[o0+1])));
      float s2 = 1.f/(1.f + expf(-(acc[j][2] + bias[o0+2])));
      float s3 = 1.f/(1.f + expf(-(acc[j][3] + bias[o0+3])));
      __half2* vp = (__half2*)(VAL + base);
      vp[0] = f2h2(s0, s1);
      vp[1] = f2h2(s2, s3);
    }
  } else {
    #pragma unroll
    for (int j = 0; j < 4; ++j) {
      int b = bg*4 + j;
      size_t vbase = ((size_t)b*N_NODES + n)*128 + 64 + o0;
      size_t obase = (size_t)b*(N_NODES*64) + n*64 + o0;  // 4-elem aligned
      float r0[4];
      #pragma unroll
      for (int i = 0; i < 4; ++i) {
        float cc = tanhf(acc[j][i] + bias[o0 + i]);
        float u  = __half2float(VALu[vbase + i]);
        float h  = hx[obase + i];
        r0[i] = u*h + (1.f - u)*cc;
      }
      *reinterpret_cast<float4*>(out + obase) = make_float4(r0[0], r0[1], r0[2], r0[3]);
    }
  }
}

extern "C" void kernel_launch(void* const* d_in, const int* in_sizes, int n_in,
                              void* d_out, int out_size, void* d_ws, size_t ws_size,
                              hipStream_t stream)
{
  const float* inp      = (const float*)d_in[0];
  const float* hx       = (const float*)d_in[1];
  const float* supp     = (const float*)d_in[2];
  const float* mu_w_ru  = (const float*)d_in[3];
  const float* ls_w_ru  = (const float*)d_in[4];
  const float* mu_b_ru  = (const float*)d_in[5];
  const float* ls_b_ru  = (const float*)d_in[6];
  const float* eps_w_ru = (const float*)d_in[7];
  const float* eps_b_ru = (const float*)d_in[8];
  const float* mu_w_c   = (const float*)d_in[9];
  const float* ls_w_c   = (const float*)d_in[10];
  const float* mu_b_c   = (const float*)d_in[11];
  const float* ls_b_c   = (const float*)d_in[12];
  const float* eps_w_c  = (const float*)d_in[13];
  const float* eps_b_c  = (const float*)d_in[14];
  float* out = (float*)d_out;

  char* wsp = (char*)d_ws;
  size_t off = 0;
  auto take = [&](size_t bytes) -> void* {
    void* p = wsp + off;
    off = (off + bytes + 255) & ~(size_t)255;
    return p;
  };
  const size_t NSF = (size_t)N_NODES * WROW;                 // 9,216,000
  h16*   Xh  = (h16*)  take(5*NSF*sizeof(h16));              //  92.2 MB
  h16*   VAL = (h16*)  take((size_t)BATCH*N_NODES*128*sizeof(h16)); // 32.8 MB
  float* Wru = (float*)take(KTOT*128*sizeof(float));
  float* bru = (float*)take(128*sizeof(float));
  float* Wc  = (float*)take(KTOT*64*sizeof(float));
  float* bc  = (float*)take(64*sizeof(float));
  unsigned short* ellc = (unsigned short*)take((size_t)2*N_NODES*ELLW*sizeof(unsigned short));
  float* ellv= (float*)take((size_t)2*N_NODES*ELLW*sizeof(float));
  int*   cnt = (int*)  take((size_t)2*N_NODES*sizeof(int));
  // total ~128.3 MB (fits: R4 ran at this footprint)
  (void)ws_size;

  hipMemsetAsync(cnt, 0, (size_t)2*N_NODES*sizeof(int), stream);
  k_weights<<<249, 256, 0, stream>>>(mu_w_ru, ls_w_ru, eps_w_ru,
                                     mu_b_ru, ls_b_ru, eps_b_ru,
                                     mu_w_c, ls_w_c, eps_w_c,
                                     mu_b_c, ls_b_c, eps_b_c,
                                     Wru, bru, Wc, bc);
  k_ell<<<dim3(8, N_NODES, 2), 256, 0, stream>>>(supp, ellc, ellv, cnt);

  h16* X0 = Xh;
  h16* X1 = Xh +   NSF;
  h16* X2 = Xh + 2*NSF;
  h16* X3 = Xh + 3*NSF;
  h16* X4 = Xh + 4*NSF;
  const size_t WLDS = (size_t)DFEAT*3*64*sizeof(float);   // 50,688 B

  for (int pass = 0; pass < 2; ++pass) {
    k_build0<<<N_NODES, 256, 0, stream>>>(inp, hx, VAL, X0, pass);
    k_spmm <<<dim3(N_NODES, 2), 256, 0, stream>>>(X1, X3, X0, ellc, ellv, cnt);
    k_cheb <<<dim3(N_NODES, 2), 256, 0, stream>>>(X2, X4, X1, X3, X0, ellc, ellv, cnt);
    if (pass == 0)
      k_proj<<<dim3(N_NODES, 2), 256, WLDS, stream>>>(Xh, Wru, bru, VAL,
                                                      nullptr, nullptr, nullptr, 128, 0);
    else
      k_proj<<<dim3(N_NODES, 1), 256, WLDS, stream>>>(Xh, Wc, bc, nullptr,
                                                      hx, VAL, out, 64, 1);
  }
}